// Round 2
// baseline (15519.641 us; speedup 1.0000x reference)
//
#include <hip/hip_runtime.h>
#include <hip/hip_bf16.h>
#include <hip/hip_cooperative_groups.h>

namespace cg = cooperative_groups;

#define Bn 64
#define Sn 256
#define Cn 512
#define Hn 1024
#define On 1024
#define NL 3   // L-1 inner layers

// ------------------------------------------------------------------
// prep: h_init[l][h][b] = hid_layer[b][l+1][h]   (transpose to h-major)
// ------------------------------------------------------------------
__global__ void prep_kernel(const float* __restrict__ hid, float* __restrict__ h_init) {
    int idx = blockIdx.x * blockDim.x + threadIdx.x;   // over NL*Hn*Bn
    if (idx >= NL * Hn * Bn) return;
    int b = idx & (Bn - 1);
    int h = (idx >> 6) & (Hn - 1);
    int l = idx >> 16;                                  // / (Hn*Bn)
    h_init[idx] = hid[(size_t)b * 4 * Hn + (size_t)(l + 1) * Hn + h];
}

// ------------------------------------------------------------------
// G1: h0proj[b][g] = fc1_b[g] + sum_h h0[b][h] * fc1_w[g][512+h]
// ------------------------------------------------------------------
__global__ __launch_bounds__(256) void g1_kernel(const float* __restrict__ hid,
                                                 const float* __restrict__ fc1_w,
                                                 const float* __restrict__ fc1_b,
                                                 float* __restrict__ h0proj) {
    __shared__ __align__(16) float h0s[Hn];
    int b = blockIdx.x;
    int tid = threadIdx.x;
    for (int i = tid; i < Hn; i += 256) h0s[i] = hid[(size_t)b * 4 * Hn + i];
    __syncthreads();
    for (int g = tid; g < Hn; g += 256) {
        const float* wr = fc1_w + (size_t)g * (Cn + Hn) + Cn;   // row g, h-part
        float acc = 0.f;
        for (int k = 0; k < Hn; k += 4) {
            float4 w4 = *(const float4*)&wr[k];
            acc = fmaf(w4.x, h0s[k + 0], acc);
            acc = fmaf(w4.y, h0s[k + 1], acc);
            acc = fmaf(w4.z, h0s[k + 2], acc);
            acc = fmaf(w4.w, h0s[k + 3], acc);
        }
        h0proj[b * Hn + g] = acc + fc1_b[g];
    }
}

// ------------------------------------------------------------------
// G2: T0[m][g] = tanh( X[m][:512] @ fc1_w[g][:512] + h0proj[m&63][g] )
//     m = t*64 + b ; X row ptr = x + b*S*C + t*C
// 64x64 tile, K-chunked (64), K-major LDS, 4x4 register tiles.
// ------------------------------------------------------------------
__global__ __launch_bounds__(256) void g2_kernel(const float* __restrict__ x,
                                                 const float* __restrict__ fc1_w,
                                                 const float* __restrict__ h0proj,
                                                 float* __restrict__ t0) {
    __shared__ __align__(16) float As[64][64];   // [k][m]
    __shared__ __align__(16) float Bs[64][64];   // [k][g]
    int tid = threadIdx.x;
    int bx = blockIdx.x;          // m-tile = t (since 64 b's per tile)
    int g0 = blockIdx.y * 64;
    int ml = tid & 63;
    int kq = tid >> 6;
    const float* xrow = x + (size_t)ml * (Sn * Cn) + (size_t)bx * Cn;      // b=ml, t=bx
    const float* wrow = fc1_w + (size_t)(g0 + ml) * (Cn + Hn);             // x-part cols
    int wave = tid >> 6, lane = tid & 63;
    int tm = (wave & 1) * 32 + (lane & 7) * 4;
    int tg = (wave >> 1) * 32 + (lane >> 3) * 4;
    float acc[4][4] = {};
    for (int kc = 0; kc < Cn / 64; ++kc) {
#pragma unroll
        for (int r = 0; r < 4; ++r) {
            int kk = kq * 16 + r * 4;
            float4 v = *(const float4*)&xrow[kc * 64 + kk];
            As[kk + 0][ml] = v.x; As[kk + 1][ml] = v.y;
            As[kk + 2][ml] = v.z; As[kk + 3][ml] = v.w;
        }
#pragma unroll
        for (int r = 0; r < 4; ++r) {
            int kk = kq * 16 + r * 4;
            float4 v = *(const float4*)&wrow[kc * 64 + kk];
            Bs[kk + 0][ml] = v.x; Bs[kk + 1][ml] = v.y;
            Bs[kk + 2][ml] = v.z; Bs[kk + 3][ml] = v.w;
        }
        __syncthreads();
#pragma unroll 4
        for (int k = 0; k < 64; ++k) {
            float4 a4 = *(const float4*)&As[k][tm];
            float4 b4 = *(const float4*)&Bs[k][tg];
            float av[4] = {a4.x, a4.y, a4.z, a4.w};
            float bv[4] = {b4.x, b4.y, b4.z, b4.w};
#pragma unroll
            for (int i = 0; i < 4; ++i)
#pragma unroll
                for (int j = 0; j < 4; ++j)
                    acc[i][j] = fmaf(av[i], bv[j], acc[i][j]);
        }
        __syncthreads();
    }
    int m0 = bx * 64;
#pragma unroll
    for (int i = 0; i < 4; ++i) {
        int m = m0 + tm + i;
        int b = tm + i;                         // m & 63
        const float* hp = h0proj + (size_t)b * Hn + g0 + tg;
        float4 o;
        o.x = tanhf(acc[i][0] + hp[0]);
        o.y = tanhf(acc[i][1] + hp[1]);
        o.z = tanhf(acc[i][2] + hp[2]);
        o.w = tanhf(acc[i][3] + hp[3]);
        *(float4*)&t0[(size_t)m * Hn + g0 + tg] = o;
    }
}

// ------------------------------------------------------------------
// G3: logits[m][o] = relu( temp[m][:] @ fc2_w[o][:] + fc2_b[o] )
// ------------------------------------------------------------------
__global__ __launch_bounds__(256) void g3_kernel(const float* __restrict__ temp,
                                                 const float* __restrict__ fc2_w,
                                                 const float* __restrict__ fc2_b,
                                                 float* __restrict__ logits) {
    __shared__ __align__(16) float As[64][64];
    __shared__ __align__(16) float Bs[64][64];
    int tid = threadIdx.x;
    int bx = blockIdx.x;
    int g0 = blockIdx.y * 64;
    int ml = tid & 63;
    int kq = tid >> 6;
    const float* arow = temp + (size_t)(bx * 64 + ml) * Hn;
    const float* wrow = fc2_w + (size_t)(g0 + ml) * Hn;
    int wave = tid >> 6, lane = tid & 63;
    int tm = (wave & 1) * 32 + (lane & 7) * 4;
    int tg = (wave >> 1) * 32 + (lane >> 3) * 4;
    float acc[4][4] = {};
    for (int kc = 0; kc < Hn / 64; ++kc) {
#pragma unroll
        for (int r = 0; r < 4; ++r) {
            int kk = kq * 16 + r * 4;
            float4 v = *(const float4*)&arow[kc * 64 + kk];
            As[kk + 0][ml] = v.x; As[kk + 1][ml] = v.y;
            As[kk + 2][ml] = v.z; As[kk + 3][ml] = v.w;
        }
#pragma unroll
        for (int r = 0; r < 4; ++r) {
            int kk = kq * 16 + r * 4;
            float4 v = *(const float4*)&wrow[kc * 64 + kk];
            Bs[kk + 0][ml] = v.x; Bs[kk + 1][ml] = v.y;
            Bs[kk + 2][ml] = v.z; Bs[kk + 3][ml] = v.w;
        }
        __syncthreads();
#pragma unroll 4
        for (int k = 0; k < 64; ++k) {
            float4 a4 = *(const float4*)&As[k][tm];
            float4 b4 = *(const float4*)&Bs[k][tg];
            float av[4] = {a4.x, a4.y, a4.z, a4.w};
            float bv[4] = {b4.x, b4.y, b4.z, b4.w};
#pragma unroll
            for (int i = 0; i < 4; ++i)
#pragma unroll
                for (int j = 0; j < 4; ++j)
                    acc[i][j] = fmaf(av[i], bv[j], acc[i][j]);
        }
        __syncthreads();
    }
    int m0 = bx * 64;
#pragma unroll
    for (int i = 0; i < 4; ++i) {
        int m = m0 + tm + i;
        float4 o;
        o.x = fmaxf(acc[i][0] + fc2_b[g0 + tg + 0], 0.f);
        o.y = fmaxf(acc[i][1] + fc2_b[g0 + tg + 1], 0.f);
        o.z = fmaxf(acc[i][2] + fc2_b[g0 + tg + 2], 0.f);
        o.w = fmaxf(acc[i][3] + fc2_b[g0 + tg + 3], 0.f);
        *(float4*)&logits[(size_t)m * Hn + g0 + tg] = o;
    }
}

// ------------------------------------------------------------------
// Cooperative recurrence: 192 WGs = 3 l * 16 g-slices(64) * 4 K-splits(256)
// Per step p: stage B (= sum of prev partials + bias; p==0 -> h_init),
// compute 64g x 64b x 256k partials into P[p&1][ks], fold(t=p-2) by WGs<16.
// gs==0 WGs also write bias-added h_sum (consumed by the fold).
// ------------------------------------------------------------------
__global__ __launch_bounds__(256) void recur_kernel(
        const float* __restrict__ lin_w, const float* __restrict__ lin_b,
        const float* __restrict__ h_init, const float* __restrict__ t0,
        float* __restrict__ temp, float* __restrict__ P, float* __restrict__ h_sum) {
    __shared__ __align__(16) float As[64][64];   // [k][g]
    __shared__ __align__(16) float Bs[64][64];   // [k][b]
    __shared__ __align__(16) float F[64][65];    // fold tile (padded)
    int tid = threadIdx.x;
    int w = blockIdx.x;
    int l = w >> 6;
    int r = w & 63;
    int gs = r >> 2, ks = r & 3;
    int g0 = gs * 64, k0 = ks * 256;
    const size_t KS = (size_t)NL * Hn * Bn;      // 196608
    const size_t PL = 4 * KS;                    // one parity of P
    int wave = tid >> 6, lane = tid & 63;
    int tg = (wave & 1) * 32 + (lane & 7) * 4;
    int tb = (wave >> 1) * 32 + (lane >> 3) * 4;
    int ml = tid & 63, kq = tid >> 6;
    cg::grid_group grid = cg::this_grid();

    for (int p = 0; p < Sn + 2; ++p) {
        // ---------------- fold(t = p-2), 16 designated WGs ----------------
        if (p >= 2 && w < 16) {
            int t = p - 2;
            int fg0 = w * 64;
            const float* hs = h_sum + (size_t)(t & 1) * KS;
            for (int e = tid; e < 4096; e += 256) {       // load T0 tile, g-fast
                int gg = e & 63, bb = e >> 6;
                F[bb][gg] = t0[((size_t)t * Bn + bb) * Hn + fg0 + gg];
            }
            __syncthreads();
            for (int e = tid; e < 4096; e += 256) {       // apply 3 tanh folds, b-fast
                int bb = e & 63, gg = e >> 6;
                size_t hoff = (size_t)(fg0 + gg) * Bn + bb;
                float tv = F[bb][gg];
                tv = tanhf(hs[hoff] + tv);
                tv = tanhf(hs[hoff + (size_t)Hn * Bn] + tv);
                tv = tanhf(hs[hoff + (size_t)2 * Hn * Bn] + tv);
                F[bb][gg] = tv;
            }
            __syncthreads();
            for (int e = tid; e < 4096; e += 256) {       // store temp tile, g-fast
                int gg = e & 63, bb = e >> 6;
                temp[((size_t)t * Bn + bb) * Hn + fg0 + gg] = F[bb][gg];
            }
        }
        // ---------------- recurrence step p ----------------
        if (p < Sn) {
            float acc[4][4] = {};
            int par_src = (p - 1) & 1;
            const float* Psrc = P + (size_t)par_src * PL;
            float* hs_dst = h_sum + (size_t)par_src * KS;
            for (int kc = 0; kc < 4; ++kc) {
                // stage A chunk: As[kk][g] = lin_w[l][g0+g][k0+kc*64+kk]
                const float* wrow = lin_w + ((size_t)l * Hn + (g0 + ml)) * Hn + k0 + kc * 64;
#pragma unroll
                for (int rr = 0; rr < 4; ++rr) {
                    int kk = kq * 16 + rr * 4;
                    float4 v = *(const float4*)&wrow[kk];
                    As[kk + 0][ml] = v.x; As[kk + 1][ml] = v.y;
                    As[kk + 2][ml] = v.z; As[kk + 3][ml] = v.w;
                }
                // stage B chunk: Bs[kk][b] = h_prev[l][k0+kc*64+kk][b]
                for (int idx = tid; idx < 1024; idx += 256) {
                    int bq = (idx & 15) * 4;
                    int kk = idx >> 4;
                    int hidx = k0 + kc * 64 + kk;
                    size_t off = ((size_t)l * Hn + hidx) * Bn + bq;
                    float4 v;
                    if (p == 0) {
                        v = *(const float4*)&h_init[off];
                    } else {
                        float4 v0 = *(const float4*)&Psrc[off];
                        float4 v1 = *(const float4*)&Psrc[off + KS];
                        float4 v2 = *(const float4*)&Psrc[off + 2 * KS];
                        float4 v3 = *(const float4*)&Psrc[off + 3 * KS];
                        float bias = lin_b[l * Hn + hidx];
                        v.x = v0.x + v1.x + v2.x + v3.x + bias;
                        v.y = v0.y + v1.y + v2.y + v3.y + bias;
                        v.z = v0.z + v1.z + v2.z + v3.z + bias;
                        v.w = v0.w + v1.w + v2.w + v3.w + bias;
                        if (gs == 0) *(float4*)&hs_dst[off] = v;
                    }
                    *(float4*)&Bs[kk][bq] = v;
                }
                __syncthreads();
#pragma unroll 4
                for (int kk = 0; kk < 64; ++kk) {
                    float4 a4 = *(const float4*)&As[kk][tg];
                    float4 b4 = *(const float4*)&Bs[kk][tb];
                    float av[4] = {a4.x, a4.y, a4.z, a4.w};
                    float bv[4] = {b4.x, b4.y, b4.z, b4.w};
#pragma unroll
                    for (int i = 0; i < 4; ++i)
#pragma unroll
                        for (int j = 0; j < 4; ++j)
                            acc[i][j] = fmaf(av[i], bv[j], acc[i][j]);
                }
                __syncthreads();
            }
            // write partials P[p&1][ks][l][g][b]
            float* Pdst = P + (size_t)(p & 1) * PL + (size_t)ks * KS;
#pragma unroll
            for (int i = 0; i < 4; ++i) {
                float4 o = make_float4(acc[i][0], acc[i][1], acc[i][2], acc[i][3]);
                *(float4*)&Pdst[((size_t)l * Hn + (g0 + tg + i)) * Bn + tb] = o;
            }
        } else if (p == Sn && gs == 0) {
            // final h_sum writeback for step Sn-1 (no compute this phase)
            int par_src = (Sn - 1) & 1;
            const float* Psrc = P + (size_t)par_src * PL;
            float* hs_dst = h_sum + (size_t)par_src * KS;
            for (int idx = tid; idx < 4096; idx += 256) {   // 256k x 16 b-quads
                int bq = (idx & 15) * 4;
                int kk = idx >> 4;
                int hidx = k0 + kk;
                size_t off = ((size_t)l * Hn + hidx) * Bn + bq;
                float4 v0 = *(const float4*)&Psrc[off];
                float4 v1 = *(const float4*)&Psrc[off + KS];
                float4 v2 = *(const float4*)&Psrc[off + 2 * KS];
                float4 v3 = *(const float4*)&Psrc[off + 3 * KS];
                float bias = lin_b[l * Hn + hidx];
                float4 v;
                v.x = v0.x + v1.x + v2.x + v3.x + bias;
                v.y = v0.y + v1.y + v2.y + v3.y + bias;
                v.z = v0.z + v1.z + v2.z + v3.z + bias;
                v.w = v0.w + v1.w + v2.w + v3.w + bias;
                *(float4*)&hs_dst[off] = v;
            }
        }
        grid.sync();
    }
}

// ------------------------------------------------------------------
// softmax over each 1024-row of logits -> f32 out (reference output is f32!)
// ------------------------------------------------------------------
__global__ __launch_bounds__(256) void softmax_kernel(const float* __restrict__ logits,
                                                      float* __restrict__ out) {
    __shared__ float redm[4];
    __shared__ float reds[4];
    __shared__ float bcast[2];
    int row = blockIdx.x, tid = threadIdx.x;
    const float* in = logits + (size_t)row * On;
    float4 v = *(const float4*)&in[tid * 4];
    float mx = fmaxf(fmaxf(v.x, v.y), fmaxf(v.z, v.w));
#pragma unroll
    for (int o = 32; o > 0; o >>= 1) mx = fmaxf(mx, __shfl_down(mx, o));
    if ((tid & 63) == 0) redm[tid >> 6] = mx;
    __syncthreads();
    if (tid == 0) bcast[0] = fmaxf(fmaxf(redm[0], redm[1]), fmaxf(redm[2], redm[3]));
    __syncthreads();
    float M = bcast[0];
    float e0 = expf(v.x - M), e1 = expf(v.y - M), e2 = expf(v.z - M), e3 = expf(v.w - M);
    float s = e0 + e1 + e2 + e3;
#pragma unroll
    for (int o = 32; o > 0; o >>= 1) s += __shfl_down(s, o);
    if ((tid & 63) == 0) reds[tid >> 6] = s;
    __syncthreads();
    if (tid == 0) bcast[1] = reds[0] + reds[1] + reds[2] + reds[3];
    __syncthreads();
    float inv = 1.0f / bcast[1];
    float4 o4 = make_float4(e0 * inv, e1 * inv, e2 * inv, e3 * inv);
    *(float4*)&out[(size_t)row * On + tid * 4] = o4;
}

// ------------------------------------------------------------------
extern "C" void kernel_launch(void* const* d_in, const int* in_sizes, int n_in,
                              void* d_out, int out_size, void* d_ws, size_t ws_size,
                              hipStream_t stream) {
    const float* x     = (const float*)d_in[0];
    const float* hid   = (const float*)d_in[1];
    const float* fc1_w = (const float*)d_in[2];
    const float* fc1_b = (const float*)d_in[3];
    const float* fc2_w = (const float*)d_in[4];
    const float* fc2_b = (const float*)d_in[5];
    const float* lin_w = (const float*)d_in[6];
    const float* lin_b = (const float*)d_in[7];
    float* out = (float*)d_out;

    float* ws     = (float*)d_ws;
    float* temp   = ws;                                    // S*B*H
    float* t0log  = temp  + (size_t)Sn * Bn * Hn;          // S*B*H (T0, then logits)
    float* P      = t0log + (size_t)Sn * Bn * Hn;          // 2*4*NL*H*B
    float* h_sum  = P     + (size_t)2 * 4 * NL * Hn * Bn;  // 2*NL*H*B
    float* h_init = h_sum + (size_t)2 * NL * Hn * Bn;      // NL*H*B
    float* h0proj = h_init + (size_t)NL * Hn * Bn;         // B*H

    prep_kernel<<<(NL * Hn * Bn + 255) / 256, 256, 0, stream>>>(hid, h_init);
    g1_kernel<<<Bn, 256, 0, stream>>>(hid, fc1_w, fc1_b, h0proj);
    g2_kernel<<<dim3(Sn * Bn / 64, Hn / 64), 256, 0, stream>>>(x, fc1_w, h0proj, t0log);

    const float* t0c = t0log;
    void* args[] = { (void*)&lin_w, (void*)&lin_b, (void*)&h_init, (void*)&t0c,
                     (void*)&temp, (void*)&P, (void*)&h_sum };
    hipLaunchCooperativeKernel((const void*)recur_kernel, dim3(192), dim3(256),
                               args, 0, stream);

    g3_kernel<<<dim3(Sn * Bn / 64, Hn / 64), 256, 0, stream>>>(temp, fc2_w, fc2_b, t0log);
    softmax_kernel<<<Sn * Bn, 256, 0, stream>>>(t0log, out);
}